// Round 5
// baseline (3486.182 us; speedup 1.0000x reference)
//
#include <hip/hip_runtime.h>
#include <hip/hip_bf16.h>

// Problem constants
#define BQ   8
#define NLQ  1024
#define NQ   2048
#define DQ   128
#define NBLK 512   // 2 blocks/CU * 256 CUs — all co-resident (72KB LDS, VGPR<=256)

typedef __attribute__((ext_vector_type(4))) float f32x4;
typedef __attribute__((ext_vector_type(8))) short bf16x8;

__device__ __forceinline__ unsigned short bfbits(float f) {
  __hip_bfloat16 h = __float2bfloat16(f);
  return __builtin_bit_cast(unsigned short, h);
}
__device__ __forceinline__ float sigm(float x) { return 1.f / (1.f + expf(-x)); }

// packed bf16 pair add (truncating round — threshold slack is huge)
__device__ __forceinline__ unsigned int bfadd2(unsigned int a, unsigned int b) {
  float alo = __builtin_bit_cast(float, a << 16);
  float ahi = __builtin_bit_cast(float, a & 0xffff0000u);
  float blo = __builtin_bit_cast(float, b << 16);
  float bhi = __builtin_bit_cast(float, b & 0xffff0000u);
  float lo = alo + blo, hi = ahi + bhi;
  return (__builtin_bit_cast(unsigned int, hi) & 0xffff0000u) |
         (__builtin_bit_cast(unsigned int, lo) >> 16);
}

// async global->LDS, 16B per lane. LDS dest is wave-uniform base + lane*16.
__device__ __forceinline__ void g2l16(const void* g, void* l) {
  __builtin_amdgcn_global_load_lds(
      (__attribute__((address_space(1))) void*)(uintptr_t)g,
      (__attribute__((address_space(3))) void*)(uint32_t)(uintptr_t)l,
      16, 0, 0);
}

// Grid barrier: one fresh slot per barrier (slots zeroed by memset each call).
// Release on arrive (ACQ_REL RMW), relaxed polls, one acquire load at exit.
__device__ __forceinline__ void gsync(unsigned* slot, int t) {
  __syncthreads();
  if (t == 0) {
    __hip_atomic_fetch_add(slot, 1u, __ATOMIC_ACQ_REL, __HIP_MEMORY_SCOPE_AGENT);
    while (__hip_atomic_load(slot, __ATOMIC_RELAXED, __HIP_MEMORY_SCOPE_AGENT) <
           (unsigned)NBLK)
      __builtin_amdgcn_s_sleep(8);
    (void)__hip_atomic_load(slot, __ATOMIC_ACQUIRE, __HIP_MEMORY_SCOPE_AGENT);
  }
  __syncthreads();
}

// ---------------------------------------------------------------------------
// Phase: msgs split-K-2. Tile 64x128, BK=64, 4 waves, 3-buffer, vmcnt(6).
// pid -> (bm = pid&31, bz = pid>>5); bz = batch*2 + khalf.
// ---------------------------------------------------------------------------
__device__ __forceinline__ void phase_msgs(
    __hip_bfloat16* sm, const __hip_bfloat16* __restrict__ adj,
    const __hip_bfloat16* __restrict__ hT, __hip_bfloat16* __restrict__ msP,
    int pid, int t) {
  const int lane = t & 63, w = t >> 6;
  const int wr = (w >> 1) & 1, wc = w & 1;
  const int bm = pid & 31;
  const int bz = pid >> 5;
  const int batch = bz >> 1, kh = bz & 1;
  const __hip_bfloat16* aB = adj + (size_t)batch * NQ * NQ + (size_t)bm * 64 * NQ + kh * 1024;
  const __hip_bfloat16* bB = hT + (size_t)batch * DQ * NQ + kh * 1024;
  const int srA = w * 16 + (lane >> 3);
  const int srB = w * 32 + (lane >> 3);
  const int swzCol = ((lane & 7) ^ (lane >> 3)) << 3;
  const int lr = lane & 15, lh = lane >> 4;
  const int rswz = (lr & 7) << 3;
  f32x4 acc[2][4] = {};
  auto As = [&](int bi) -> __hip_bfloat16* { return sm + bi * 4096; };
  auto Bs = [&](int bi) -> __hip_bfloat16* { return sm + 12288 + bi * 8192; };
  auto stage = [&](int bi, int tt) {
    const int k = tt * 64;
#pragma unroll
    for (int q = 0; q < 2; ++q)
      g2l16(aB + (size_t)(srA + q * 8) * NQ + k + swzCol, (char*)As(bi) + w * 2048 + q * 1024);
#pragma unroll
    for (int q = 0; q < 4; ++q)
      g2l16(bB + (size_t)(srB + q * 8) * NQ + k + swzCol, (char*)Bs(bi) + w * 4096 + q * 1024);
  };
  stage(0, 0);
  stage(1, 1);
  asm volatile("s_waitcnt vmcnt(6)" ::: "memory");
  __builtin_amdgcn_s_barrier();
  int cur = 0;
  const int nt = 16;
  for (int tt = 0; tt < nt; ++tt) {
    bf16x8 av[2][2], bv[2][4];
#pragma unroll
    for (int kk = 0; kk < 2; ++kk) {
#pragma unroll
      for (int m = 0; m < 2; ++m)
        av[kk][m] = *(const bf16x8*)&As(cur)[(wr * 32 + m * 16 + lr) * 64 +
                                            ((kk * 32 + lh * 8) ^ rswz)];
#pragma unroll
      for (int n = 0; n < 4; ++n)
        bv[kk][n] = *(const bf16x8*)&Bs(cur)[(wc * 64 + n * 16 + lr) * 64 +
                                             ((kk * 32 + lh * 8) ^ rswz)];
    }
    if (tt + 2 < nt) {
      int bi = cur + 2; if (bi >= 3) bi -= 3;
      stage(bi, tt + 2);
    }
    __builtin_amdgcn_s_setprio(1);
#pragma unroll
    for (int kk = 0; kk < 2; ++kk)
#pragma unroll
      for (int m = 0; m < 2; ++m)
#pragma unroll
        for (int n = 0; n < 4; ++n)
          acc[m][n] = __builtin_amdgcn_mfma_f32_16x16x32_bf16(av[kk][m], bv[kk][n],
                                                              acc[m][n], 0, 0, 0);
    __builtin_amdgcn_s_setprio(0);
    if (tt < nt - 2) {
      asm volatile("s_waitcnt vmcnt(6)" ::: "memory");
      __builtin_amdgcn_s_barrier();
    } else if (tt == nt - 2) {
      asm volatile("s_waitcnt vmcnt(0)" ::: "memory");
      __builtin_amdgcn_s_barrier();
    }
    ++cur; if (cur == 3) cur = 0;
  }
  __hip_bfloat16* out = msP + (size_t)kh * (BQ * NQ * DQ) + (size_t)batch * NQ * DQ;
#pragma unroll
  for (int m = 0; m < 2; ++m) {
    const int row0 = bm * 64 + wr * 32 + m * 16 + lh * 4;
#pragma unroll
    for (int n = 0; n < 4; ++n) {
      const int col = wc * 64 + n * 16 + lr;
#pragma unroll
      for (int r = 0; r < 4; ++r)
        out[(size_t)(row0 + r) * DQ + col] = __float2bfloat16(acc[m][n][r]);
    }
  }
}

// ---------------------------------------------------------------------------
// Phase: zr. C[16384 x 256] = [h | ms0+ms1] @ wzr^T. Tile 64x128, nt=4.
// pid -> (bm = pid&255, bn = pid>>8). Reg-sum path for k>=128.
// ---------------------------------------------------------------------------
__device__ __forceinline__ void phase_zr(
    __hip_bfloat16* sm, const __hip_bfloat16* __restrict__ A0,
    const __hip_bfloat16* __restrict__ ms, const __hip_bfloat16* __restrict__ BT,
    const float* __restrict__ bias0, const float* __restrict__ bias1,
    const float* __restrict__ hF, float* __restrict__ zF,
    __hip_bfloat16* __restrict__ rh, int pid, int t) {
  const int lane = t & 63, w = t >> 6;
  const int wr = (w >> 1) & 1, wc = w & 1;
  const int bm = pid & 255, bn = pid >> 8;
  const int swzCol = ((lane & 7) ^ (lane >> 3)) << 3;
  const int lr = lane & 15, lh = lane >> 4;
  const int rswz = (lr & 7) << 3;
  const size_t msStride = (size_t)BQ * NQ * DQ;
  const int nt = 4;  // K=256
  f32x4 acc[2][4] = {};
  uint4 p0[2], p1[2];
  auto As = [&](int bi) -> __hip_bfloat16* { return sm + bi * 4096; };
  auto Bs = [&](int bi) -> __hip_bfloat16* { return sm + 12288 + bi * 8192; };
  auto stageB = [&](int bi, int tt) {
#pragma unroll
    for (int q = 0; q < 4; ++q)
      g2l16(BT + (size_t)(bn * 128 + w * 32 + q * 8 + (lane >> 3)) * 256 + tt * 64 + swzCol,
            (char*)Bs(bi) + w * 4096 + q * 1024);
  };
  auto stageA = [&](int bi, int tt) -> bool {
    const int k0 = tt * 64;
    if (k0 < 128) {
#pragma unroll
      for (int q = 0; q < 2; ++q)
        g2l16(A0 + (size_t)(bm * 64 + w * 16 + q * 8 + (lane >> 3)) * 128 + k0 + swzCol,
              (char*)As(bi) + w * 2048 + q * 1024);
      return false;
    }
    const size_t base = (size_t)(bm * 64 + w * 16 + (lane >> 3)) * 128 + (k0 - 128) + swzCol;
#pragma unroll
    for (int q = 0; q < 2; ++q) {
      p0[q] = *(const uint4*)(ms + base + (size_t)q * 8 * 128);
      p1[q] = *(const uint4*)(ms + msStride + base + (size_t)q * 8 * 128);
    }
    return true;
  };
  auto finalize = [&](int bi) {
#pragma unroll
    for (int q = 0; q < 2; ++q) {
      uint4 s;
      s.x = bfadd2(p0[q].x, p1[q].x);
      s.y = bfadd2(p0[q].y, p1[q].y);
      s.z = bfadd2(p0[q].z, p1[q].z);
      s.w = bfadd2(p0[q].w, p1[q].w);
      *(uint4*)((char*)As(bi) + w * 2048 + q * 1024 + lane * 16) = s;
    }
  };
  stageA(0, 0); stageB(0, 0);
  stageA(1, 1); stageB(1, 1);
  asm volatile("s_waitcnt vmcnt(6)" ::: "memory");
  __builtin_amdgcn_s_barrier();
  int cur = 0;
  for (int tt = 0; tt < nt; ++tt) {
    bf16x8 av[2][2], bv[2][4];
#pragma unroll
    for (int kk = 0; kk < 2; ++kk) {
#pragma unroll
      for (int m = 0; m < 2; ++m)
        av[kk][m] = *(const bf16x8*)&As(cur)[(wr * 32 + m * 16 + lr) * 64 +
                                            ((kk * 32 + lh * 8) ^ rswz)];
#pragma unroll
      for (int n = 0; n < 4; ++n)
        bv[kk][n] = *(const bf16x8*)&Bs(cur)[(wc * 64 + n * 16 + lr) * 64 +
                                             ((kk * 32 + lh * 8) ^ rswz)];
    }
    bool reg = false;
    int bi = cur + 2; if (bi >= 3) bi -= 3;
    if (tt + 2 < nt) {
      reg = stageA(bi, tt + 2);
      stageB(bi, tt + 2);
    }
    __builtin_amdgcn_s_setprio(1);
#pragma unroll
    for (int kk = 0; kk < 2; ++kk)
#pragma unroll
      for (int m = 0; m < 2; ++m)
#pragma unroll
        for (int n = 0; n < 4; ++n)
          acc[m][n] = __builtin_amdgcn_mfma_f32_16x16x32_bf16(av[kk][m], bv[kk][n],
                                                              acc[m][n], 0, 0, 0);
    __builtin_amdgcn_s_setprio(0);
    if (reg) finalize(bi);
    if (tt < nt - 2) {
      if (reg)
        asm volatile("s_waitcnt vmcnt(4) lgkmcnt(0)" ::: "memory");
      else
        asm volatile("s_waitcnt vmcnt(6) lgkmcnt(0)" ::: "memory");
      __builtin_amdgcn_s_barrier();
    } else if (tt == nt - 2) {
      asm volatile("s_waitcnt vmcnt(0) lgkmcnt(0)" ::: "memory");
      __builtin_amdgcn_s_barrier();
    }
    ++cur; if (cur == 3) cur = 0;
  }
#pragma unroll
  for (int m = 0; m < 2; ++m) {
    const int gRow = bm * 64 + wr * 32 + m * 16 + lh * 4;
#pragma unroll
    for (int n = 0; n < 4; ++n) {
      const int col = bn * 128 + wc * 64 + n * 16 + lr;
      f32x4 v = acc[m][n];
      if (col < 128) {  // z (bn==0, block-uniform)
        const float bb = bias0[col];
#pragma unroll
        for (int r = 0; r < 4; ++r)
          zF[(size_t)(gRow + r) * DQ + col] = sigm(v[r] + bb);
      } else {          // r -> r*h
        const int c = col - 128;
        const float bb = bias1[c];
#pragma unroll
        for (int r = 0; r < 4; ++r) {
          size_t idx = (size_t)(gRow + r) * DQ + c;
          float rr = sigm(v[r] + bb);
          rh[idx] = __float2bfloat16(rr * hF[idx]);
        }
      }
    }
  }
}

// ---------------------------------------------------------------------------
// Phase: 32-row token GEMM (in-proj EPI=3, ht+GRU EPI=2). Tile 32x128, 512
// blocks x 32 rows. EPI2: K=256 with reg-sum for k>=128; EPI3: K=128 direct.
// ---------------------------------------------------------------------------
template <int EPI>
__device__ __forceinline__ void token32(
    __hip_bfloat16* sm, const __hip_bfloat16* __restrict__ A0,
    const __hip_bfloat16* __restrict__ ms, const __hip_bfloat16* __restrict__ BT,
    const float* __restrict__ bias0, float* __restrict__ hF, float* __restrict__ zF,
    __hip_bfloat16* __restrict__ bf0, __hip_bfloat16* __restrict__ bf1,
    int pid, int t) {
  const int lane = t & 63, w = t >> 6;
  const int wr = (w >> 1) & 1, wc = w & 1;
  const int swzCol = ((lane & 7) ^ (lane >> 3)) << 3;
  const int lr = lane & 15, lh = lane >> 4;
  const int rswz = (lr & 7) << 3;
  const size_t msStride = (size_t)BQ * NQ * DQ;
  const int K = (EPI == 2) ? 256 : 128;
  const int nt = K >> 6;
  f32x4 acc[4] = {};
  uint4 p0, p1;
  const int arow = pid * 32 + w * 8 + (lane >> 3);
  auto As = [&](int bi) -> __hip_bfloat16* { return sm + bi * 2048; };
  auto Bs = [&](int bi) -> __hip_bfloat16* { return sm + 12288 + bi * 8192; };
  auto stageB = [&](int bi, int tt) {
#pragma unroll
    for (int q = 0; q < 4; ++q)
      g2l16(BT + (size_t)(w * 32 + q * 8 + (lane >> 3)) * K + tt * 64 + swzCol,
            (char*)Bs(bi) + w * 4096 + q * 1024);
  };
  auto stageA = [&](int bi, int tt) -> bool {
    const int k0 = tt * 64;
    if (EPI == 3 || k0 < 128) {
      g2l16(A0 + (size_t)arow * 128 + k0 + swzCol, (char*)As(bi) + w * 1024);
      return false;
    }
    const size_t base = (size_t)arow * 128 + (k0 - 128) + swzCol;
    p0 = *(const uint4*)(ms + base);
    p1 = *(const uint4*)(ms + msStride + base);
    return true;
  };
  auto finalize = [&](int bi) {
    uint4 s;
    s.x = bfadd2(p0.x, p1.x);
    s.y = bfadd2(p0.y, p1.y);
    s.z = bfadd2(p0.z, p1.z);
    s.w = bfadd2(p0.w, p1.w);
    *(uint4*)((char*)As(bi) + w * 1024 + lane * 16) = s;
  };
  stageA(0, 0); stageB(0, 0);
  stageA(1, 1); stageB(1, 1);
  asm volatile("s_waitcnt vmcnt(5)" ::: "memory");
  __builtin_amdgcn_s_barrier();
  int cur = 0;
  for (int tt = 0; tt < nt; ++tt) {
    bf16x8 av[2], bv[2][4];
#pragma unroll
    for (int kk = 0; kk < 2; ++kk) {
      av[kk] = *(const bf16x8*)&As(cur)[(wr * 16 + lr) * 64 + ((kk * 32 + lh * 8) ^ rswz)];
#pragma unroll
      for (int n = 0; n < 4; ++n)
        bv[kk][n] = *(const bf16x8*)&Bs(cur)[(wc * 64 + n * 16 + lr) * 64 +
                                             ((kk * 32 + lh * 8) ^ rswz)];
    }
    bool reg = false;
    int bi = cur + 2; if (bi >= 3) bi -= 3;
    if (tt + 2 < nt) {
      reg = stageA(bi, tt + 2);
      stageB(bi, tt + 2);
    }
    __builtin_amdgcn_s_setprio(1);
#pragma unroll
    for (int kk = 0; kk < 2; ++kk)
#pragma unroll
      for (int n = 0; n < 4; ++n)
        acc[n] = __builtin_amdgcn_mfma_f32_16x16x32_bf16(av[kk], bv[kk][n], acc[n], 0, 0, 0);
    __builtin_amdgcn_s_setprio(0);
    if (reg) finalize(bi);
    if (tt < nt - 2) {
      if (reg)
        asm volatile("s_waitcnt vmcnt(4) lgkmcnt(0)" ::: "memory");
      else
        asm volatile("s_waitcnt vmcnt(5) lgkmcnt(0)" ::: "memory");
      __builtin_amdgcn_s_barrier();
    } else if (tt == nt - 2) {
      asm volatile("s_waitcnt vmcnt(0) lgkmcnt(0)" ::: "memory");
      __builtin_amdgcn_s_barrier();
    }
    ++cur; if (cur == 3) cur = 0;
  }
  const int gRow = pid * 32 + wr * 16 + lh * 4;
#pragma unroll
  for (int n = 0; n < 4; ++n) {
    const int col = wc * 64 + n * 16 + lr;
    f32x4 v = acc[n];
    const float bb = bias0[col];
    ushort4 us;
    unsigned short* up = (unsigned short*)&us;
#pragma unroll
    for (int r = 0; r < 4; ++r) {
      size_t idx = (size_t)(gRow + r) * DQ + col;
      float hn;
      if constexpr (EPI == 2) {
        float tv = tanhf(v[r] + bb);
        float zv = zF[idx];
        float hv = hF[idx];
        hn = zv * hv + (1.f - zv) * tv;
      } else {
        hn = v[r] + bb;
      }
      hF[idx] = hn;
      bf0[idx] = __float2bfloat16(hn);
      up[r] = bfbits(hn);
    }
    const int bb_ = gRow >> 11;
    const int nl = gRow & 2047;
    *(ushort4*)((char*)bf1 + ((size_t)bb_ * (DQ * NQ) + (size_t)col * NQ + nl) * 2) = us;
  }
}

// ---------------------------------------------------------------------------
// Persistent mega-kernel: setup + 5 x (in + 3 x (msgs, zr, ht)) + x-copy.
// ---------------------------------------------------------------------------
__global__ __launch_bounds__(256, 2) void mega(
    const float* __restrict__ inputad,
    const int* __restrict__ node, const int* __restrict__ text,
    const int* __restrict__ line,
    const float* __restrict__ te, const float* __restrict__ te1,
    const float* __restrict__ ugW, const float* __restrict__ rgW,
    const float* __restrict__ htW, const float* __restrict__ inW,
    const float* __restrict__ in_b, const float* __restrict__ ug_b,
    const float* __restrict__ rg_b, const float* __restrict__ ht_b,
    __hip_bfloat16* __restrict__ adjbf, float* __restrict__ hF,
    float* __restrict__ zF, __hip_bfloat16* __restrict__ hbf,
    __hip_bfloat16* __restrict__ hT, __hip_bfloat16* __restrict__ msbf,
    __hip_bfloat16* __restrict__ rhbf, __hip_bfloat16* __restrict__ wzrT,
    __hip_bfloat16* __restrict__ htTw, __hip_bfloat16* __restrict__ inTw,
    float* __restrict__ outX, unsigned* __restrict__ bar) {
  __shared__ __align__(16) __hip_bfloat16 smBuf[36864];  // 72 KB
  const int pid = blockIdx.x;
  const int t = threadIdx.x;
  int bslot = 0;
  auto SYNC = [&]() { gsync(bar + (bslot++), t); };

  // ---- setup: adj->bf16, weight pack, embeddings ----
  {
    const int gid = pid * 256 + t, gs = NBLK * 256;
    const float4* af4 = (const float4*)inputad;
    ushort4* ao4 = (ushort4*)adjbf;
    for (int i = gid; i < BQ * NQ * NQ / 4; i += gs) {
      float4 v = af4[i];
      ushort4 o;
      o.x = bfbits(v.x); o.y = bfbits(v.y); o.z = bfbits(v.z); o.w = bfbits(v.w);
      ao4[i] = o;
    }
    const int W1 = 5 * 256 * 256, W2 = 5 * 128 * 256, W3 = 5 * 128 * 128;
    for (int i = gid; i < W1 + W2 + W3; i += gs) {
      if (i < W1) {
        int i0 = i >> 16, r = i & 65535, nn = r >> 8, k = r & 255;
        float v = (nn < 128) ? ugW[(i0 * 256 + k) * 128 + nn]
                             : rgW[(i0 * 256 + k) * 128 + nn - 128];
        wzrT[i] = __float2bfloat16(v);
      } else if (i < W1 + W2) {
        int j = i - W1;
        int i0 = j >> 15, r = j & 32767, nn = r >> 8, k = r & 255;
        htTw[j] = __float2bfloat16(htW[(i0 * 256 + k) * 128 + nn]);
      } else {
        int j2 = i - W1 - W2;
        int i0 = j2 >> 14, r = j2 & 16383, nn = r >> 7, k = r & 127;
        inTw[j2] = __float2bfloat16(inW[(i0 * 128 + k) * 128 + nn]);
      }
    }
    for (int i = gid; i < BQ * NQ * DQ; i += gs) {
      int d = i & 127, p = (i >> 7) & 2047, b = i >> 18;
      float v;
      if (p < NLQ) {
        if (d < 127) v = te[(size_t)node[b * NLQ + p] * 127 + d];
        else v = (float)text[b * NLQ + p];
      } else {
        v = te1[(size_t)line[b * NLQ + (p - NLQ)] * 128 + d];
      }
      hbf[i] = __float2bfloat16(v);
    }
  }
  SYNC();

  for (int i = 0; i < 5; ++i) {
    token32<3>(smBuf, hbf, nullptr, inTw + i * 128 * 128, in_b + i * 128,
               hF, nullptr, hbf, hT, pid, t);
    SYNC();
    for (int s = 0; s < 3; ++s) {
      phase_msgs(smBuf, adjbf, hT, msbf, pid, t);
      SYNC();
      phase_zr(smBuf, hbf, msbf, wzrT + i * 256 * 256, ug_b + i * 128, rg_b + i * 128,
               hF, zF, rhbf, pid, t);
      SYNC();
      token32<2>(smBuf, rhbf, msbf, htTw + i * 128 * 256, ht_b + i * 128,
                 hF, zF, hbf, hT, pid, t);
      SYNC();
    }
  }

  // ---- x output copy (fp32, first NL rows of each batch) ----
  {
    const int gid = pid * 256 + t;
    const float4* h4 = (const float4*)hF;
    float4* o4 = (float4*)outX;
    for (int i2 = gid; i2 < BQ * NLQ * 32; i2 += NBLK * 256) {
      int r = i2 >> 5, c = i2 & 31, b = r >> 10, n = r & 1023;
      o4[i2] = h4[((size_t)b * NQ + n) * 32 + c];
    }
  }
}

__device__ __forceinline__ float waveMax(float v) {
#pragma unroll
  for (int m = 32; m; m >>= 1) v = fmaxf(v, __shfl_xor(v, m, 64));
  return v;
}
__device__ __forceinline__ float waveSum(float v) {
#pragma unroll
  for (int m = 32; m; m >>= 1) v += __shfl_xor(v, m, 64);
  return v;
}

// logits = h[:, :NL] @ res2_W + b; mask; softmax; loss. 1024 thr, 1 row/thr.
__global__ __launch_bounds__(1024) void final_k(const float* __restrict__ h,
                                                const float* __restrict__ w2,
                                                const float* __restrict__ b2,
                                                const int* __restrict__ node,
                                                const float* __restrict__ res,
                                                float* __restrict__ outLoss,
                                                float* __restrict__ outSm) {
  int b = blockIdx.x, t = threadIdx.x;
  __shared__ float lw[128];
  __shared__ float red[16];
  __shared__ float bc;
  if (t < 128) lw[t] = w2[t];
  __syncthreads();
  const float* hr = h + ((size_t)b * NQ + t) * DQ;
  float s = 0.f;
#pragma unroll
  for (int d = 0; d < 128; d += 4) {
    float4 hv = *(const float4*)(hr + d);
    s += hv.x * lw[d] + hv.y * lw[d + 1] + hv.z * lw[d + 2] + hv.w * lw[d + 3];
  }
  float lg = (node[b * NLQ + t] == 2) ? (s + b2[0]) : -1e9f;
  int lane = t & 63, w = t >> 6;
  float mx = waveMax(lg);
  if (lane == 0) red[w] = mx;
  __syncthreads();
  if (t == 0) {
    float m = red[0];
#pragma unroll
    for (int i = 1; i < 16; ++i) m = fmaxf(m, red[i]);
    bc = m;
  }
  __syncthreads();
  float M = bc;
  float e = expf(lg - M);
  float sum = waveSum(e);
  __syncthreads();
  if (lane == 0) red[w] = sum;
  __syncthreads();
  if (t == 0) {
    float tot = 0.f;
#pragma unroll
    for (int i = 0; i < 16; ++i) tot += red[i];
    bc = tot;
  }
  __syncthreads();
  float sm = e / bc;
  outSm[b * NLQ + t] = sm;
  float c = fminf(fmaxf(sm, 1e-10f), 1.f);
  float loss = waveSum(-logf(c) * res[b * NLQ + t]);
  __syncthreads();
  if (lane == 0) red[w] = loss;
  __syncthreads();
  if (t == 0) {
    float tot = 0.f;
#pragma unroll
    for (int i = 0; i < 16; ++i) tot += red[i];
    outLoss[b] = tot;
  }
}

__global__ void ws_fail(float* out) {
  if (threadIdx.x == 0) out[0] = -7.0e7f;  // sentinel: workspace too small
}

// ---------------------------------------------------------------------------
extern "C" void kernel_launch(void* const* d_in, const int* in_sizes, int n_in,
                              void* d_out, int out_size, void* d_ws, size_t ws_size,
                              hipStream_t stream) {
  const int* input_node = (const int*)d_in[0];
  const float* inputad  = (const float*)d_in[2];
  const float* res      = (const float*)d_in[3];
  const int* inputtext  = (const int*)d_in[4];
  const int* linenode   = (const int*)d_in[5];
  const float* tok_emb  = (const float*)d_in[8];
  const float* tok_emb1 = (const float*)d_in[9];
  const float* in_W  = (const float*)d_in[10];
  const float* in_b  = (const float*)d_in[11];
  const float* ug_W  = (const float*)d_in[12];
  const float* ug_b  = (const float*)d_in[13];
  const float* rg_W  = (const float*)d_in[14];
  const float* rg_b  = (const float*)d_in[15];
  const float* ht_W  = (const float*)d_in[16];
  const float* ht_b  = (const float*)d_in[17];
  const float* res2_W = (const float*)d_in[18];
  const float* res2_b = (const float*)d_in[19];

  char* ws = (char*)d_ws;
  const size_t OFF_ADJ = 0;
  const size_t OFF_H   = OFF_ADJ + (size_t)BQ * NQ * NQ * 2;       // adj bf16, 67 MB
  const size_t OFF_Z   = OFF_H   + (size_t)BQ * NQ * DQ * 4;       // h fp32
  const size_t OFF_HBF = OFF_Z   + (size_t)BQ * NQ * DQ * 4;       // z fp32
  const size_t OFF_HT  = OFF_HBF + (size_t)BQ * NQ * DQ * 2;       // h bf16 row-major
  const size_t OFF_MS  = OFF_HT  + (size_t)BQ * NQ * DQ * 2;       // hT bf16 [b][d][n]
  const size_t OFF_RH  = OFF_MS  + (size_t)2 * BQ * NQ * DQ * 2;   // msgs partials x2
  const size_t OFF_WZR = OFF_RH  + (size_t)BQ * NQ * DQ * 2;       // r*h bf16
  const size_t OFF_HTW = OFF_WZR + (size_t)5 * 256 * 256 * 2;
  const size_t OFF_INW = OFF_HTW + (size_t)5 * 128 * 256 * 2;
  const size_t OFF_BAR = (OFF_INW + (size_t)5 * 128 * 128 * 2 + 255) & ~(size_t)255;
  const size_t NEED    = OFF_BAR + 1024;
  if (ws_size < NEED) {
    ws_fail<<<1, 64, 0, stream>>>((float*)d_out);
    return;
  }

  __hip_bfloat16* adjbf = (__hip_bfloat16*)(ws + OFF_ADJ);
  float* hF             = (float*)(ws + OFF_H);
  float* zF             = (float*)(ws + OFF_Z);
  __hip_bfloat16* hbf   = (__hip_bfloat16*)(ws + OFF_HBF);
  __hip_bfloat16* hT    = (__hip_bfloat16*)(ws + OFF_HT);
  __hip_bfloat16* msbf  = (__hip_bfloat16*)(ws + OFF_MS);
  __hip_bfloat16* rhbf  = (__hip_bfloat16*)(ws + OFF_RH);
  __hip_bfloat16* wzrT  = (__hip_bfloat16*)(ws + OFF_WZR);
  __hip_bfloat16* htTw  = (__hip_bfloat16*)(ws + OFF_HTW);
  __hip_bfloat16* inTw  = (__hip_bfloat16*)(ws + OFF_INW);
  unsigned* bar         = (unsigned*)(ws + OFF_BAR);

  float* outLoss = (float*)d_out;
  float* outSm = outLoss + BQ;
  float* outX = outSm + BQ * NLQ;

  hipMemsetAsync(bar, 0, 1024, stream);  // zero barrier slots (ws is poisoned 0xAA)

  mega<<<NBLK, 256, 0, stream>>>(inputad, input_node, inputtext, linenode,
                                 tok_emb, tok_emb1, ug_W, rg_W, ht_W, in_W,
                                 in_b, ug_b, rg_b, ht_b,
                                 adjbf, hF, zF, hbf, hT, msbf, rhbf,
                                 wzrT, htTw, inTw, outX, bar);

  final_k<<<8, 1024, 0, stream>>>(hF, res2_W, res2_b, input_node, res, outLoss, outSm);
}

// Round 6
// 776.235 us; speedup vs baseline: 4.4911x; 4.4911x over previous
//
#include <hip/hip_runtime.h>
#include <hip/hip_bf16.h>

// Problem constants
#define BQ   8
#define NLQ  1024
#define NQ   2048
#define DQ   128

typedef __attribute__((ext_vector_type(4))) float f32x4;
typedef __attribute__((ext_vector_type(8))) short bf16x8;

__device__ __forceinline__ unsigned short bfbits(float f) {
  __hip_bfloat16 h = __float2bfloat16(f);
  return __builtin_bit_cast(unsigned short, h);
}
__device__ __forceinline__ unsigned int pk2(float a, float b) {
  return ((unsigned int)bfbits(b) << 16) | bfbits(a);
}
__device__ __forceinline__ float sigm(float x) { return 1.f / (1.f + expf(-x)); }

// packed bf16 pair add (truncating round — threshold slack is huge)
__device__ __forceinline__ unsigned int bfadd2(unsigned int a, unsigned int b) {
  float alo = __builtin_bit_cast(float, a << 16);
  float ahi = __builtin_bit_cast(float, a & 0xffff0000u);
  float blo = __builtin_bit_cast(float, b << 16);
  float bhi = __builtin_bit_cast(float, b & 0xffff0000u);
  float lo = alo + blo, hi = ahi + bhi;
  return (__builtin_bit_cast(unsigned int, hi) & 0xffff0000u) |
         (__builtin_bit_cast(unsigned int, lo) >> 16);
}

// async global->LDS, 16B per lane. LDS dest is wave-uniform base + lane*16.
__device__ __forceinline__ void g2l16(const void* g, void* l) {
  __builtin_amdgcn_global_load_lds(
      (__attribute__((address_space(1))) void*)(uintptr_t)g,
      (__attribute__((address_space(3))) void*)(uint32_t)(uintptr_t)l,
      16, 0, 0);
}

// ---------------------------------------------------------------------------
// msgs GEMM, split-K-2 (r4-proven, unchanged). Tile 64x128, BK=64, 4 waves,
// 3-buffer, counted vmcnt(6). Grid (32,1,16) = 512 blocks.
// ---------------------------------------------------------------------------
__global__ __launch_bounds__(256) void gemm_msgs(
    const __hip_bfloat16* __restrict__ adj,   // [B][2048][2048]
    const __hip_bfloat16* __restrict__ hT,    // [B][128][2048]
    __hip_bfloat16* __restrict__ msP) {       // [2][B][2048][128]
  __shared__ __align__(16) __hip_bfloat16 As[3][64 * 64];
  __shared__ __align__(16) __hip_bfloat16 Bs[3][128 * 64];
  const int t = threadIdx.x, lane = t & 63, w = t >> 6;
  const int wr = (w >> 1) & 1, wc = w & 1;
  const int bm = blockIdx.x;
  const int batch = blockIdx.z >> 1, kh = blockIdx.z & 1;

  const __hip_bfloat16* aB = adj + (size_t)batch * NQ * NQ + (size_t)bm * 64 * NQ + kh * 1024;
  const __hip_bfloat16* bB = hT + (size_t)batch * DQ * NQ + kh * 1024;

  const int srA = w * 16 + (lane >> 3);
  const int srB = w * 32 + (lane >> 3);
  const int swzCol = ((lane & 7) ^ (lane >> 3)) << 3;
  const int lr = lane & 15, lh = lane >> 4;
  const int rswz = (lr & 7) << 3;

  f32x4 acc[2][4] = {};

  auto stage = [&](int bi, int tt) {
    const int k = tt * 64;
#pragma unroll
    for (int q = 0; q < 2; ++q)
      g2l16(aB + (size_t)(srA + q * 8) * NQ + k + swzCol, (char*)As[bi] + w * 2048 + q * 1024);
#pragma unroll
    for (int q = 0; q < 4; ++q)
      g2l16(bB + (size_t)(srB + q * 8) * NQ + k + swzCol, (char*)Bs[bi] + w * 4096 + q * 1024);
  };

  stage(0, 0);
  stage(1, 1);
  asm volatile("s_waitcnt vmcnt(6)" ::: "memory");
  __builtin_amdgcn_s_barrier();

  int cur = 0;
  const int nt = 16;
  for (int tt = 0; tt < nt; ++tt) {
    bf16x8 av[2][2], bv[2][4];
#pragma unroll
    for (int kk = 0; kk < 2; ++kk) {
#pragma unroll
      for (int m = 0; m < 2; ++m)
        av[kk][m] = *(const bf16x8*)&As[cur][(wr * 32 + m * 16 + lr) * 64 +
                                            ((kk * 32 + lh * 8) ^ rswz)];
#pragma unroll
      for (int n = 0; n < 4; ++n)
        bv[kk][n] = *(const bf16x8*)&Bs[cur][(wc * 64 + n * 16 + lr) * 64 +
                                             ((kk * 32 + lh * 8) ^ rswz)];
    }
    if (tt + 2 < nt) {
      int bi = cur + 2; if (bi >= 3) bi -= 3;
      stage(bi, tt + 2);
    }
    __builtin_amdgcn_s_setprio(1);
#pragma unroll
    for (int kk = 0; kk < 2; ++kk)
#pragma unroll
      for (int m = 0; m < 2; ++m)
#pragma unroll
        for (int n = 0; n < 4; ++n)
          acc[m][n] = __builtin_amdgcn_mfma_f32_16x16x32_bf16(av[kk][m], bv[kk][n],
                                                              acc[m][n], 0, 0, 0);
    __builtin_amdgcn_s_setprio(0);
    if (tt < nt - 2) {
      asm volatile("s_waitcnt vmcnt(6)" ::: "memory");
      __builtin_amdgcn_s_barrier();
    } else if (tt == nt - 2) {
      asm volatile("s_waitcnt vmcnt(0)" ::: "memory");
      __builtin_amdgcn_s_barrier();
    }
    ++cur; if (cur == 3) cur = 0;
  }
  __hip_bfloat16* out = msP + (size_t)kh * (BQ * NQ * DQ) + (size_t)batch * NQ * DQ;
#pragma unroll
  for (int m = 0; m < 2; ++m) {
    const int row0 = bm * 64 + wr * 32 + m * 16 + lh * 4;
#pragma unroll
    for (int n = 0; n < 4; ++n) {
      const int col = wc * 64 + n * 16 + lr;
#pragma unroll
      for (int r = 0; r < 4; ++r)
        out[(size_t)(row0 + r) * DQ + col] = __float2bfloat16(acc[m][n][r]);
    }
  }
}

// ---------------------------------------------------------------------------
// Fused GRU step: per block, 64 token rows.
//  A_comb LDS tiles: [4][64][64]  (tiles 0,1 = h ; 2,3 = ms0+ms1)
//  pass z:  [h|ms] @ ug^T  -> zreg (regs only)
//  pass r:  [h|ms] @ rg^T  -> rh = sigm(.)*h  -> rewrite tiles 0,1
//  pass ht: [rh|ms] @ ht^T -> hn = z*h+(1-z)*tanh(.)
//  DO_IN:   hn -> tiles 0,1 ; hn @ inW(next)^T -> hF/hbf/hT
//  else:    hn -> hF/hbf/hT
// ---------------------------------------------------------------------------
template <bool DO_IN>
__global__ __launch_bounds__(256, 2) void gru_k(
    const __hip_bfloat16* __restrict__ hbf_in,
    const __hip_bfloat16* __restrict__ ms,    // [2][16384][128]
    const __hip_bfloat16* __restrict__ wzr,   // [256][256] this block-i
    const __hip_bfloat16* __restrict__ htW,   // [128][256]
    const __hip_bfloat16* __restrict__ inWn,  // [128][128] next i (or null)
    const float* __restrict__ ugb, const float* __restrict__ rgb,
    const float* __restrict__ htb, const float* __restrict__ inbn,
    float* __restrict__ hF, __hip_bfloat16* __restrict__ hbf,
    __hip_bfloat16* __restrict__ hT) {
  __shared__ __align__(16) __hip_bfloat16 Asm[4 * 4096];  // 32 KB
  __shared__ __align__(16) __hip_bfloat16 Bsm[3 * 8192];  // 48 KB
  const int t = threadIdx.x, lane = t & 63, w = t >> 6;
  const int wr = (w >> 1) & 1, wc = w & 1;
  const int bm = blockIdx.x;
  const int lr = lane & 15, lh = lane >> 4;
  const int rswz = (lr & 7) << 3;
  const int swzCol = ((lane & 7) ^ (lane >> 3)) << 3;
  const int srow = lane >> 3;
  const size_t msStride = (size_t)BQ * NQ * DQ;

  auto stageB = [&](const __hip_bfloat16* BT, int ld, int bi, int tt) {
#pragma unroll
    for (int q = 0; q < 4; ++q)
      g2l16(BT + (size_t)(w * 32 + q * 8 + srow) * ld + tt * 64 + swzCol,
            (char*)Bsm + bi * 16384 + w * 4096 + q * 1024);
  };

  // ---- prologue: A tiles 0,1 from hbf; tiles 2,3 = ms0+ms1 ----
#pragma unroll
  for (int ti = 0; ti < 2; ++ti)
#pragma unroll
    for (int q = 0; q < 2; ++q)
      g2l16(hbf_in + (size_t)(bm * 64 + w * 16 + q * 8 + srow) * 128 + ti * 64 + swzCol,
            (char*)Asm + ti * 8192 + w * 2048 + q * 1024);
  uint4 p0[4], p1[4];
  {
    const size_t base = (size_t)(bm * 64 + w * 16 + srow) * 128 + swzCol;
#pragma unroll
    for (int ti = 0; ti < 2; ++ti)
#pragma unroll
      for (int q = 0; q < 2; ++q) {
        p0[ti * 2 + q] = *(const uint4*)(ms + base + ti * 64 + (size_t)q * 8 * 128);
        p1[ti * 2 + q] = *(const uint4*)(ms + msStride + base + ti * 64 + (size_t)q * 8 * 128);
      }
  }
  stageB(wzr, 256, 0, 0);
  stageB(wzr, 256, 1, 1);
#pragma unroll
  for (int ti = 0; ti < 2; ++ti)
#pragma unroll
    for (int q = 0; q < 2; ++q) {
      uint4 a = p0[ti * 2 + q], b = p1[ti * 2 + q], s;
      s.x = bfadd2(a.x, b.x); s.y = bfadd2(a.y, b.y);
      s.z = bfadd2(a.z, b.z); s.w = bfadd2(a.w, b.w);
      *(uint4*)((char*)Asm + (2 + ti) * 8192 + w * 2048 + q * 1024 + lane * 16) = s;
    }
  asm volatile("s_waitcnt vmcnt(4) lgkmcnt(0)" ::: "memory");
  __builtin_amdgcn_s_barrier();

  f32x4 acc[2][4];
  // one 64x128xK pass; A tile index == tt; B pre-staged bufs 0,1
  auto run = [&](const __hip_bfloat16* BT, int ld, int nt) {
#pragma unroll
    for (int m = 0; m < 2; ++m)
#pragma unroll
      for (int n = 0; n < 4; ++n) acc[m][n] = (f32x4){0.f, 0.f, 0.f, 0.f};
    int cur = 0;
    for (int tt = 0; tt < nt; ++tt) {
      bf16x8 av[2][2], bv[2][4];
#pragma unroll
      for (int kk = 0; kk < 2; ++kk) {
#pragma unroll
        for (int m = 0; m < 2; ++m)
          av[kk][m] = *(const bf16x8*)&Asm[tt * 4096 + (wr * 32 + m * 16 + lr) * 64 +
                                          ((kk * 32 + lh * 8) ^ rswz)];
#pragma unroll
        for (int n = 0; n < 4; ++n)
          bv[kk][n] = *(const bf16x8*)&Bsm[cur * 8192 + (wc * 64 + n * 16 + lr) * 64 +
                                           ((kk * 32 + lh * 8) ^ rswz)];
      }
      if (tt + 2 < nt) {
        int bi = cur + 2; if (bi >= 3) bi -= 3;
        stageB(BT, ld, bi, tt + 2);
      }
      __builtin_amdgcn_s_setprio(1);
#pragma unroll
      for (int kk = 0; kk < 2; ++kk)
#pragma unroll
        for (int m = 0; m < 2; ++m)
#pragma unroll
          for (int n = 0; n < 4; ++n)
            acc[m][n] = __builtin_amdgcn_mfma_f32_16x16x32_bf16(av[kk][m], bv[kk][n],
                                                                acc[m][n], 0, 0, 0);
      __builtin_amdgcn_s_setprio(0);
      if (tt < nt - 2) {
        asm volatile("s_waitcnt vmcnt(4)" ::: "memory");
        __builtin_amdgcn_s_barrier();
      } else if (tt == nt - 2) {
        asm volatile("s_waitcnt vmcnt(0)" ::: "memory");
        __builtin_amdgcn_s_barrier();
      }
      ++cur; if (cur == 3) cur = 0;
    }
  };

  f32x4 zreg[2][4], hreg[2][4];

  // ---- pass z ----
  run(wzr, 256, 4);
#pragma unroll
  for (int m = 0; m < 2; ++m)
#pragma unroll
    for (int n = 0; n < 4; ++n) {
      const int col = wc * 64 + n * 16 + lr;
      const float zb = ugb[col];
#pragma unroll
      for (int r = 0; r < 4; ++r) zreg[m][n][r] = sigm(acc[m][n][r] + zb);
    }
  __syncthreads();

  // ---- pass r ----
  stageB(wzr + 128 * 256, 256, 0, 0);
  stageB(wzr + 128 * 256, 256, 1, 1);
  asm volatile("s_waitcnt vmcnt(4)" ::: "memory");
  __builtin_amdgcn_s_barrier();
  run(wzr + 128 * 256, 256, 4);
  __syncthreads();  // all waves done reading A tiles 0,1
  stageB(htW, 256, 0, 0);
  stageB(htW, 256, 1, 1);
#pragma unroll
  for (int m = 0; m < 2; ++m)
#pragma unroll
    for (int n = 0; n < 4; ++n) {
      const int col = wc * 64 + n * 16 + lr;
      const int ti = col >> 6, cole = col & 63;
      const float rb = rgb[col];
#pragma unroll
      for (int r = 0; r < 4; ++r) {
        const int lrow = wr * 32 + m * 16 + lh * 4 + r;
        const float hv = hF[(size_t)(bm * 64 + lrow) * DQ + col];
        hreg[m][n][r] = hv;
        const float rr = sigm(acc[m][n][r] + rb);
        Asm[ti * 4096 + lrow * 64 + (((cole >> 3) ^ (lrow & 7)) << 3) + (cole & 7)] =
            __float2bfloat16(rr * hv);
      }
    }
  asm volatile("s_waitcnt vmcnt(4) lgkmcnt(0)" ::: "memory");
  __builtin_amdgcn_s_barrier();

  // ---- pass ht ----
  run(htW, 256, 4);
  __syncthreads();

  if constexpr (DO_IN) {
    stageB(inWn, 128, 0, 0);
    stageB(inWn, 128, 1, 1);
#pragma unroll
    for (int m = 0; m < 2; ++m)
#pragma unroll
      for (int n = 0; n < 4; ++n) {
        const int col = wc * 64 + n * 16 + lr;
        const int ti = col >> 6, cole = col & 63;
        const float hb = htb[col];
#pragma unroll
        for (int r = 0; r < 4; ++r) {
          const int lrow = wr * 32 + m * 16 + lh * 4 + r;
          const float tv = tanhf(acc[m][n][r] + hb);
          const float zv = zreg[m][n][r];
          const float hn = zv * hreg[m][n][r] + (1.f - zv) * tv;
          Asm[ti * 4096 + lrow * 64 + (((cole >> 3) ^ (lrow & 7)) << 3) + (cole & 7)] =
              __float2bfloat16(hn);
        }
      }
    asm volatile("s_waitcnt vmcnt(4) lgkmcnt(0)" ::: "memory");
    __builtin_amdgcn_s_barrier();
    // ---- pass in-proj (next block) ----
    run(inWn, 128, 2);
#pragma unroll
    for (int m = 0; m < 2; ++m) {
      const int gRow = bm * 64 + wr * 32 + m * 16 + lh * 4;
#pragma unroll
      for (int n = 0; n < 4; ++n) {
        const int col = wc * 64 + n * 16 + lr;
        const float ib = inbn[col];
        ushort4 us;
        unsigned short* up = (unsigned short*)&us;
#pragma unroll
        for (int r = 0; r < 4; ++r) {
          const float hn = acc[m][n][r] + ib;
          hF[(size_t)(gRow + r) * DQ + col] = hn;
          hbf[(size_t)(gRow + r) * DQ + col] = __float2bfloat16(hn);
          up[r] = bfbits(hn);
        }
        const int bb_ = gRow >> 11;
        const int nl = gRow & 2047;
        *(ushort4*)((char*)hT + ((size_t)bb_ * (DQ * NQ) + (size_t)col * NQ + nl) * 2) = us;
      }
    }
  } else {
#pragma unroll
    for (int m = 0; m < 2; ++m) {
      const int gRow = bm * 64 + wr * 32 + m * 16 + lh * 4;
#pragma unroll
      for (int n = 0; n < 4; ++n) {
        const int col = wc * 64 + n * 16 + lr;
        const float hb = htb[col];
        ushort4 us;
        unsigned short* up = (unsigned short*)&us;
#pragma unroll
        for (int r = 0; r < 4; ++r) {
          const float tv = tanhf(acc[m][n][r] + hb);
          const float zv = zreg[m][n][r];
          const float hn = zv * hreg[m][n][r] + (1.f - zv) * tv;
          hF[(size_t)(gRow + r) * DQ + col] = hn;
          hbf[(size_t)(gRow + r) * DQ + col] = __float2bfloat16(hn);
          up[r] = bfbits(hn);
        }
        const int bb_ = gRow >> 11;
        const int nl = gRow & 2047;
        *(ushort4*)((char*)hT + ((size_t)bb_ * (DQ * NQ) + (size_t)col * NQ + nl) * 2) = us;
      }
    }
  }
}

// ---------------------------------------------------------------------------
// in0: build x (embeddings) into LDS + in-proj block 0. 256 blocks x 64 rows.
// ---------------------------------------------------------------------------
__global__ __launch_bounds__(256, 2) void in0_k(
    const int* __restrict__ node, const int* __restrict__ text,
    const int* __restrict__ line,
    const float* __restrict__ te, const float* __restrict__ te1,
    const __hip_bfloat16* __restrict__ inW, const float* __restrict__ inb,
    float* __restrict__ hF, __hip_bfloat16* __restrict__ hbf,
    __hip_bfloat16* __restrict__ hT) {
  __shared__ __align__(16) __hip_bfloat16 Asm[2 * 4096];
  __shared__ __align__(16) __hip_bfloat16 Bsm[2 * 8192];
  const int t = threadIdx.x, lane = t & 63, w = t >> 6;
  const int wr = (w >> 1) & 1, wc = w & 1;
  const int bm = blockIdx.x;
  const int lr = lane & 15, lh = lane >> 4;
  const int rswz = (lr & 7) << 3;
  const int swzCol = ((lane & 7) ^ (lane >> 3)) << 3;
  const int srow = lane >> 3;

  // stage B (inW[0]: [128][128]) both K-tiles
#pragma unroll
  for (int bi = 0; bi < 2; ++bi)
#pragma unroll
    for (int q = 0; q < 4; ++q)
      g2l16(inW + (size_t)(w * 32 + q * 8 + srow) * 128 + bi * 64 + swzCol,
            (char*)Bsm + bi * 16384 + w * 4096 + q * 1024);

  // build x rows into Asm tiles 0,1 (swizzled b128 writes)
  {
    const int lrow = t >> 2;             // 0..63
    const int gRow = bm * 64 + lrow;
    const int b = gRow >> 11, p = gRow & 2047;
    const int c0 = (t & 3) * 32;
    float vals[32];
    if (p < NLQ) {
      const int id = node[b * NLQ + p];
      const float tx = (float)text[b * NLQ + p];
#pragma unroll
      for (int j = 0; j < 32; ++j) {
        const int col = c0 + j;
        vals[j] = (col < 127) ? te[(size_t)id * 127 + col] : tx;
      }
    } else {
      const int id = line[b * NLQ + (p - NLQ)];
#pragma unroll
      for (int j = 0; j < 32; ++j) vals[j] = te1[(size_t)id * 128 + c0 + j];
    }
#pragma unroll
    for (int k = 0; k < 4; ++k) {
      const int col = c0 + k * 8;
      const int ti = col >> 6, cole = col & 63;
      uint4 u;
      u.x = pk2(vals[k * 8 + 0], vals[k * 8 + 1]);
      u.y = pk2(vals[k * 8 + 2], vals[k * 8 + 3]);
      u.z = pk2(vals[k * 8 + 4], vals[k * 8 + 5]);
      u.w = pk2(vals[k * 8 + 6], vals[k * 8 + 7]);
      *(uint4*)((char*)Asm + ti * 8192 + lrow * 128 +
                (((cole >> 3) ^ (lrow & 7)) << 4)) = u;
    }
  }
  __syncthreads();  // drains vmcnt + lgkm: B and A both ready

  f32x4 acc[2][4] = {};
  for (int tt = 0; tt < 2; ++tt) {
    bf16x8 av[2][2], bv[2][4];
#pragma unroll
    for (int kk = 0; kk < 2; ++kk) {
#pragma unroll
      for (int m = 0; m < 2; ++m)
        av[kk][m] = *(const bf16x8*)&Asm[tt * 4096 + (wr * 32 + m * 16 + lr) * 64 +
                                        ((kk * 32 + lh * 8) ^ rswz)];
#pragma unroll
      for (int n = 0; n < 4; ++n)
        bv[kk][n] = *(const bf16x8*)&Bsm[tt * 8192 + (wc * 64 + n * 16 + lr) * 64 +
                                         ((kk * 32 + lh * 8) ^ rswz)];
    }
#pragma unroll
    for (int kk = 0; kk < 2; ++kk)
#pragma unroll
      for (int m = 0; m < 2; ++m)
#pragma unroll
        for (int n = 0; n < 4; ++n)
          acc[m][n] = __builtin_amdgcn_mfma_f32_16x16x32_bf16(av[kk][m], bv[kk][n],
                                                              acc[m][n], 0, 0, 0);
  }
#pragma unroll
  for (int m = 0; m < 2; ++m) {
    const int gRow = bm * 64 + wr * 32 + m * 16 + lh * 4;
#pragma unroll
    for (int n = 0; n < 4; ++n) {
      const int col = wc * 64 + n * 16 + lr;
      const float ib = inb[col];
      ushort4 us;
      unsigned short* up = (unsigned short*)&us;
#pragma unroll
      for (int r = 0; r < 4; ++r) {
        const float hn = acc[m][n][r] + ib;
        hF[(size_t)(gRow + r) * DQ + col] = hn;
        hbf[(size_t)(gRow + r) * DQ + col] = __float2bfloat16(hn);
        up[r] = bfbits(hn);
      }
      const int bb_ = gRow >> 11;
      const int nl = gRow & 2047;
      *(ushort4*)((char*)hT + ((size_t)bb_ * (DQ * NQ) + (size_t)col * NQ + nl) * 2) = us;
    }
  }
}

// ---------------------------------------------------------------------------
__global__ void cvt_adj(const float4* __restrict__ in, ushort4* __restrict__ out, int n4) {
  int stride = gridDim.x * blockDim.x;
  for (int i = blockIdx.x * blockDim.x + threadIdx.x; i < n4; i += stride) {
    float4 v = in[i];
    ushort4 o;
    o.x = bfbits(v.x); o.y = bfbits(v.y); o.z = bfbits(v.z); o.w = bfbits(v.w);
    out[i] = o;
  }
}

// Pack weights to bf16, transposed to N x K row-major.
__global__ void pack_weights(const float* __restrict__ ugW, const float* __restrict__ rgW,
                             const float* __restrict__ htW, const float* __restrict__ inW,
                             __hip_bfloat16* __restrict__ wzrT, __hip_bfloat16* __restrict__ htT,
                             __hip_bfloat16* __restrict__ inT) {
  int idx = blockIdx.x * 256 + threadIdx.x;
  if (idx < 5 * 256 * 256) {  // wzrT[i][n][k], n<128 -> ug, else rg
    int i = idx >> 16, r = idx & 65535, nn = r >> 8, k = r & 255;
    float v = (nn < 128) ? ugW[(i * 256 + k) * 128 + nn] : rgW[(i * 256 + k) * 128 + nn - 128];
    wzrT[idx] = __float2bfloat16(v);
    return;
  }
  int j = idx - 5 * 256 * 256;
  if (j < 5 * 128 * 256) {  // htT[i][n][k]
    int i = j >> 15, r = j & 32767, nn = r >> 8, k = r & 255;
    htT[j] = __float2bfloat16(htW[(i * 256 + k) * 128 + nn]);
    return;
  }
  int j2 = j - 5 * 128 * 256;
  if (j2 < 5 * 128 * 128) {  // inT[i][n][k]
    int i = j2 >> 14, r = j2 & 16383, nn = r >> 7, k = r & 127;
    inT[j2] = __float2bfloat16(inW[(i * 128 + k) * 128 + nn]);
  }
}

__device__ __forceinline__ float waveMax(float v) {
#pragma unroll
  for (int m = 32; m; m >>= 1) v = fmaxf(v, __shfl_xor(v, m, 64));
  return v;
}
__device__ __forceinline__ float waveSum(float v) {
#pragma unroll
  for (int m = 32; m; m >>= 1) v += __shfl_xor(v, m, 64);
  return v;
}

// logits + mask + softmax + loss; also copies x rows to outX. 1 row/thread.
__global__ __launch_bounds__(1024) void final_k(const float* __restrict__ h,
                                                const float* __restrict__ w2,
                                                const float* __restrict__ b2,
                                                const int* __restrict__ node,
                                                const float* __restrict__ res,
                                                float* __restrict__ outLoss,
                                                float* __restrict__ outSm,
                                                float* __restrict__ outX) {
  int b = blockIdx.x, t = threadIdx.x;
  __shared__ float lw[128];
  __shared__ float red[16];
  __shared__ float bc;
  if (t < 128) lw[t] = w2[t];
  __syncthreads();
  const float* hr = h + ((size_t)b * NQ + t) * DQ;
  float* xr = outX + ((size_t)b * NLQ + t) * DQ;
  float s = 0.f;
#pragma unroll
  for (int d = 0; d < 128; d += 4) {
    float4 hv = *(const float4*)(hr + d);
    *(float4*)(xr + d) = hv;
    s += hv.x * lw[d] + hv.y * lw[d + 1] + hv.z * lw[d + 2] + hv.w * lw[d + 3];
  }
  float lg = (node[b * NLQ + t] == 2) ? (s + b2[0]) : -1e9f;
  int lane = t & 63, w = t >> 6;
  float mx = waveMax(lg);
  if (lane == 0) red[w] = mx;
  __syncthreads();
  if (t == 0) {
    float m = red[0];
#pragma unroll
    for (int i = 1; i < 16; ++i) m = fmaxf(m, red[i]);
    bc = m;
  }
  __syncthreads();
  float M = bc;
  float e = expf(lg - M);
  float sum = waveSum(e);
  __syncthreads();
  if (lane == 0) red[w] = sum;
  __syncthreads();
  if (t == 0) {
    float tot = 0.f;
#pragma unroll
    for (int i = 0; i < 16; ++i) tot += red[i];
    bc = tot;
  }
  __syncthreads();
  float sm = e / bc;
  outSm[b * NLQ + t] = sm;
  float c = fminf(fmaxf(sm, 1e-10f), 1.f);
  float loss = waveSum(-logf(c) * res[b * NLQ + t]);
  __syncthreads();
  if (lane == 0) red[w] = loss;
  __syncthreads();
  if (t == 0) {
    float tot = 0.f;
#pragma unroll
    for (int i = 0; i < 16; ++i) tot += red[i];
    outLoss[b] = tot;
  }
}

__global__ void ws_fail(float* out) {
  if (threadIdx.x == 0) out[0] = -7.0e7f;  // sentinel: workspace too small
}

// ---------------------------------------------------------------------------
extern "C" void kernel_launch(void* const* d_in, const int* in_sizes, int n_in,
                              void* d_out, int out_size, void* d_ws, size_t ws_size,
                              hipStream_t stream) {
  const int* input_node = (const int*)d_in[0];
  const float* inputad  = (const float*)d_in[2];
  const float* res      = (const float*)d_in[3];
  const int* inputtext  = (const int*)d_in[4];
  const int* linenode   = (const int*)d_in[5];
  const float* tok_emb  = (const float*)d_in[8];
  const float* tok_emb1 = (const float*)d_in[9];
  const float* in_W  = (const float*)d_in[10];
  const float* in_b  = (const float*)d_in[11];
  const float* ug_W  = (const float*)d_in[12];
  const float* ug_b  = (const float*)d_in[13];
  const float* rg_W  = (const float*)d_in[14];
  const float* rg_b  = (const float*)d_in[15];
  const float* ht_W  = (const float*)d_in[16];
  const float* ht_b  = (const float*)d_in[17];
  const float* res2_W = (const float*)d_in[18];
  const float* res2_b = (const float*)d_in[19];

  char* ws = (char*)d_ws;
  const size_t OFF_ADJ = 0;
  const size_t OFF_H   = OFF_ADJ + (size_t)BQ * NQ * NQ * 2;       // adj bf16, 67 MB
  const size_t OFF_HBF = OFF_H   + (size_t)BQ * NQ * DQ * 4;       // h fp32
  const size_t OFF_HT  = OFF_HBF + (size_t)BQ * NQ * DQ * 2;       // h bf16 row-major
  const size_t OFF_MS  = OFF_HT  + (size_t)BQ * NQ * DQ * 2;       // hT bf16 [b][d][n]
  const size_t OFF_WZR = OFF_MS  + (size_t)2 * BQ * NQ * DQ * 2;   // msgs partials x2
  const size_t OFF_HTW = OFF_WZR + (size_t)5 * 256 * 256 * 2;
  const size_t OFF_INW = OFF_HTW + (size_t)5 * 128 * 256 * 2;
  const size_t NEED    = OFF_INW + (size_t)5 * 128 * 128 * 2;      // ~90 MB
  if (ws_size < NEED) {
    ws_fail<<<1, 64, 0, stream>>>((float*)d_out);
    return;
  }

  __hip_bfloat16* adjbf = (__hip_bfloat16*)(ws + OFF_ADJ);
  float* hF             = (float*)(ws + OFF_H);
  __hip_bfloat16* hbf   = (__hip_bfloat16*)(ws + OFF_HBF);
  __hip_bfloat16* hT    = (__hip_bfloat16*)(ws + OFF_HT);
  __hip_bfloat16* msbf  = (__hip_bfloat16*)(ws + OFF_MS);
  __hip_bfloat16* wzrT  = (__hip_bfloat16*)(ws + OFF_WZR);
  __hip_bfloat16* htTw  = (__hip_bfloat16*)(ws + OFF_HTW);
  __hip_bfloat16* inTw  = (__hip_bfloat16*)(ws + OFF_INW);

  float* outLoss = (float*)d_out;
  float* outSm = outLoss + BQ;
  float* outX = outSm + BQ * NLQ;

  pack_weights<<<2240, 256, 0, stream>>>(ug_W, rg_W, ht_W, in_W, wzrT, htTw, inTw);
  in0_k<<<256, 256, 0, stream>>>(input_node, inputtext, linenode, tok_emb, tok_emb1,
                                 inTw, in_b, hF, hbf, hT);
  cvt_adj<<<4096, 256, 0, stream>>>((const float4*)inputad, (ushort4*)adjbf,
                                    (int)((size_t)BQ * NQ * NQ / 4));

  for (int i = 0; i < 5; ++i) {
    for (int s = 0; s < 3; ++s) {
      gemm_msgs<<<dim3(32, 1, 16), 256, 0, stream>>>(adjbf, hT, msbf);
      const bool doin = (s == 2 && i < 4);
      if (doin)
        gru_k<true><<<256, 256, 0, stream>>>(
            hbf, msbf, wzrT + i * 65536, htTw + i * 32768, inTw + (i + 1) * 16384,
            ug_b + i * 128, rg_b + i * 128, ht_b + i * 128, in_b + (i + 1) * 128,
            hF, hbf, hT);
      else
        gru_k<false><<<256, 256, 0, stream>>>(
            hbf, msbf, wzrT + i * 65536, htTw + i * 32768, nullptr,
            ug_b + i * 128, rg_b + i * 128, ht_b + i * 128, nullptr,
            hF, hbf, hT);
    }
  }

  final_k<<<8, 1024, 0, stream>>>(hF, res2_W, res2_b, input_node, res,
                                  outLoss, outSm, outX);
}

// Round 7
// 667.361 us; speedup vs baseline: 5.2238x; 1.1631x over previous
//
#include <hip/hip_runtime.h>
#include <hip/hip_bf16.h>

// Problem constants
#define BQ   8
#define NLQ  1024
#define NQ   2048
#define DQ   128

typedef __attribute__((ext_vector_type(4))) float f32x4;
typedef __attribute__((ext_vector_type(8))) short bf16x8;
typedef __attribute__((ext_vector_type(2))) unsigned long long u64x2;

__device__ __forceinline__ unsigned short bfbits(float f) {
  __hip_bfloat16 h = __float2bfloat16(f);
  return __builtin_bit_cast(unsigned short, h);
}
__device__ __forceinline__ unsigned int pk2(float a, float b) {
  return ((unsigned int)bfbits(b) << 16) | bfbits(a);
}
__device__ __forceinline__ float sigm(float x) { return 1.f / (1.f + expf(-x)); }

// byte permutation within a 128-byte chunk so that one ds_read_b128 yields
// two consecutive-kk fp8 MFMA operands: stored pos p holds source col
// c = kk2*64 + half*32 + lh*8 + j  where p = kk2*64 + lh*16 + half*8 + j
__device__ __forceinline__ int pi128(int c) {
  return (c & 64) | ((c & 24) << 1) | ((c & 32) >> 2) | (c & 7);
}

// packed bf16 pair add (truncating round — threshold slack is huge)
__device__ __forceinline__ unsigned int bfadd2(unsigned int a, unsigned int b) {
  float alo = __builtin_bit_cast(float, a << 16);
  float ahi = __builtin_bit_cast(float, a & 0xffff0000u);
  float blo = __builtin_bit_cast(float, b << 16);
  float bhi = __builtin_bit_cast(float, b & 0xffff0000u);
  float lo = alo + blo, hi = ahi + bhi;
  return (__builtin_bit_cast(unsigned int, hi) & 0xffff0000u) |
         (__builtin_bit_cast(unsigned int, lo) >> 16);
}

// async global->LDS, 16B per lane. LDS dest is wave-uniform base + lane*16.
__device__ __forceinline__ void g2l16(const void* g, void* l) {
  __builtin_amdgcn_global_load_lds(
      (__attribute__((address_space(1))) void*)(uintptr_t)g,
      (__attribute__((address_space(3))) void*)(uint32_t)(uintptr_t)l,
      16, 0, 0);
}

// ---------------------------------------------------------------------------
// msgs GEMM in FP8, split-K-2: msP[kh][b] = adj[b][:,kh-half] @ h[kh-half][:]
// adj8/hT8 are fp8 e4m3 (adj scaled by 2^13), pi-permuted per 128-chunk.
// Tile 64(M) x 128(N), BK=128 fp8 (= 128B rows, same staging geometry as the
// proven bf16 BK=64 kernel). 3-buffer LDS, counted vmcnt(6). Grid (32,1,16).
// ---------------------------------------------------------------------------
__global__ __launch_bounds__(256) void gemm_msgs(
    const unsigned char* __restrict__ adj8,   // [B][2048][2048]
    const unsigned char* __restrict__ hT8,    // [B][128][2048]
    __hip_bfloat16* __restrict__ msP) {       // [2][B][2048][128]
  __shared__ __align__(16) unsigned char As[3][64 * 128];    // 24 KB
  __shared__ __align__(16) unsigned char Bs[3][128 * 128];   // 48 KB
  const int t = threadIdx.x, lane = t & 63, w = t >> 6;
  const int wr = (w >> 1) & 1, wc = w & 1;
  const int bm = blockIdx.x;
  const int batch = blockIdx.z >> 1, kh = blockIdx.z & 1;

  const unsigned char* aB = adj8 + (size_t)batch * NQ * NQ + (size_t)bm * 64 * NQ + kh * 1024;
  const unsigned char* bB = hT8 + (size_t)batch * DQ * NQ + kh * 1024;

  const int srA = w * 16 + (lane >> 3);
  const int srB = w * 32 + (lane >> 3);
  const int swzB = ((lane & 7) ^ (lane >> 3)) << 4;  // 16B-slot XOR, source side
  const int lr = lane & 15, lh = lane >> 4;
  const int rswz = (lr & 7) << 4;                    // 16B-slot XOR, read side

  f32x4 acc[2][4] = {};

  auto stage = [&](int bi, int tt) {
    const int k = tt * 128;
#pragma unroll
    for (int q = 0; q < 2; ++q)
      g2l16(aB + (size_t)(srA + q * 8) * NQ + k + swzB, (char*)As[bi] + w * 2048 + q * 1024);
#pragma unroll
    for (int q = 0; q < 4; ++q)
      g2l16(bB + (size_t)(srB + q * 8) * NQ + k + swzB, (char*)Bs[bi] + w * 4096 + q * 1024);
  };

  stage(0, 0);
  stage(1, 1);
  asm volatile("s_waitcnt vmcnt(6)" ::: "memory");
  __builtin_amdgcn_s_barrier();

  int cur = 0;
  const int nt = 8;  // 1024 / 128
  for (int tt = 0; tt < nt; ++tt) {
    u64x2 av[2][2], bv[2][4];
#pragma unroll
    for (int kk2 = 0; kk2 < 2; ++kk2) {
      const int co = (kk2 * 64 + lh * 16) ^ rswz;
#pragma unroll
      for (int m = 0; m < 2; ++m)
        av[kk2][m] = *(const u64x2*)&As[cur][(wr * 32 + m * 16 + lr) * 128 + co];
#pragma unroll
      for (int n = 0; n < 4; ++n)
        bv[kk2][n] = *(const u64x2*)&Bs[cur][(wc * 64 + n * 16 + lr) * 128 + co];
    }
    if (tt + 2 < nt) {
      int bi = cur + 2; if (bi >= 3) bi -= 3;
      stage(bi, tt + 2);
    }
    __builtin_amdgcn_s_setprio(1);
#pragma unroll
    for (int kk2 = 0; kk2 < 2; ++kk2)
#pragma unroll
      for (int hf = 0; hf < 2; ++hf)
#pragma unroll
        for (int m = 0; m < 2; ++m)
#pragma unroll
          for (int n = 0; n < 4; ++n)
            acc[m][n] = __builtin_amdgcn_mfma_f32_16x16x32_fp8_fp8(
                (long)av[kk2][m][hf], (long)bv[kk2][n][hf], acc[m][n], 0, 0, 0);
    __builtin_amdgcn_s_setprio(0);
    if (tt < nt - 2) {
      asm volatile("s_waitcnt vmcnt(6)" ::: "memory");
      __builtin_amdgcn_s_barrier();
    } else if (tt == nt - 2) {
      asm volatile("s_waitcnt vmcnt(0)" ::: "memory");
      __builtin_amdgcn_s_barrier();
    }
    ++cur; if (cur == 3) cur = 0;
  }
  __hip_bfloat16* out = msP + (size_t)kh * (BQ * NQ * DQ) + (size_t)batch * NQ * DQ;
  const float DS = 1.f / 8192.f;  // undo adj scale
#pragma unroll
  for (int m = 0; m < 2; ++m) {
    const int row0 = bm * 64 + wr * 32 + m * 16 + lh * 4;
#pragma unroll
    for (int n = 0; n < 4; ++n) {
      const int col = wc * 64 + n * 16 + lr;
#pragma unroll
      for (int r = 0; r < 4; ++r)
        out[(size_t)(row0 + r) * DQ + col] = __float2bfloat16(acc[m][n][r] * DS);
    }
  }
}

// ---------------------------------------------------------------------------
// Fused GRU step (r6-proven), epilogue now writes fp8 hT8 instead of bf16 hT.
// ---------------------------------------------------------------------------
template <bool DO_IN>
__global__ __launch_bounds__(256, 2) void gru_k(
    const __hip_bfloat16* __restrict__ hbf_in,
    const __hip_bfloat16* __restrict__ ms,    // [2][16384][128]
    const __hip_bfloat16* __restrict__ wzr,   // [256][256] this block-i
    const __hip_bfloat16* __restrict__ htW,   // [128][256]
    const __hip_bfloat16* __restrict__ inWn,  // [128][128] next i (or null)
    const float* __restrict__ ugb, const float* __restrict__ rgb,
    const float* __restrict__ htb, const float* __restrict__ inbn,
    float* __restrict__ hF, __hip_bfloat16* __restrict__ hbf,
    unsigned char* __restrict__ hT8) {
  __shared__ __align__(16) __hip_bfloat16 Asm[4 * 4096];  // 32 KB
  __shared__ __align__(16) __hip_bfloat16 Bsm[3 * 8192];  // 48 KB
  const int t = threadIdx.x, lane = t & 63, w = t >> 6;
  const int wr = (w >> 1) & 1, wc = w & 1;
  const int bm = blockIdx.x;
  const int lr = lane & 15, lh = lane >> 4;
  const int rswz = (lr & 7) << 3;
  const int swzCol = ((lane & 7) ^ (lane >> 3)) << 3;
  const int srow = lane >> 3;
  const size_t msStride = (size_t)BQ * NQ * DQ;

  auto stageB = [&](const __hip_bfloat16* BT, int ld, int bi, int tt) {
#pragma unroll
    for (int q = 0; q < 4; ++q)
      g2l16(BT + (size_t)(w * 32 + q * 8 + srow) * ld + tt * 64 + swzCol,
            (char*)Bsm + bi * 16384 + w * 4096 + q * 1024);
  };

  // ---- prologue: A tiles 0,1 from hbf; tiles 2,3 = ms0+ms1 ----
#pragma unroll
  for (int ti = 0; ti < 2; ++ti)
#pragma unroll
    for (int q = 0; q < 2; ++q)
      g2l16(hbf_in + (size_t)(bm * 64 + w * 16 + q * 8 + srow) * 128 + ti * 64 + swzCol,
            (char*)Asm + ti * 8192 + w * 2048 + q * 1024);
  uint4 p0[4], p1[4];
  {
    const size_t base = (size_t)(bm * 64 + w * 16 + srow) * 128 + swzCol;
#pragma unroll
    for (int ti = 0; ti < 2; ++ti)
#pragma unroll
      for (int q = 0; q < 2; ++q) {
        p0[ti * 2 + q] = *(const uint4*)(ms + base + ti * 64 + (size_t)q * 8 * 128);
        p1[ti * 2 + q] = *(const uint4*)(ms + msStride + base + ti * 64 + (size_t)q * 8 * 128);
      }
  }
  stageB(wzr, 256, 0, 0);
  stageB(wzr, 256, 1, 1);
#pragma unroll
  for (int ti = 0; ti < 2; ++ti)
#pragma unroll
    for (int q = 0; q < 2; ++q) {
      uint4 a = p0[ti * 2 + q], b = p1[ti * 2 + q], s;
      s.x = bfadd2(a.x, b.x); s.y = bfadd2(a.y, b.y);
      s.z = bfadd2(a.z, b.z); s.w = bfadd2(a.w, b.w);
      *(uint4*)((char*)Asm + (2 + ti) * 8192 + w * 2048 + q * 1024 + lane * 16) = s;
    }
  asm volatile("s_waitcnt vmcnt(4) lgkmcnt(0)" ::: "memory");
  __builtin_amdgcn_s_barrier();

  f32x4 acc[2][4];
  auto run = [&](const __hip_bfloat16* BT, int ld, int nt) {
#pragma unroll
    for (int m = 0; m < 2; ++m)
#pragma unroll
      for (int n = 0; n < 4; ++n) acc[m][n] = (f32x4){0.f, 0.f, 0.f, 0.f};
    int cur = 0;
    for (int tt = 0; tt < nt; ++tt) {
      bf16x8 av[2][2], bv[2][4];
#pragma unroll
      for (int kk = 0; kk < 2; ++kk) {
#pragma unroll
        for (int m = 0; m < 2; ++m)
          av[kk][m] = *(const bf16x8*)&Asm[tt * 4096 + (wr * 32 + m * 16 + lr) * 64 +
                                          ((kk * 32 + lh * 8) ^ rswz)];
#pragma unroll
        for (int n = 0; n < 4; ++n)
          bv[kk][n] = *(const bf16x8*)&Bsm[cur * 8192 + (wc * 64 + n * 16 + lr) * 64 +
                                           ((kk * 32 + lh * 8) ^ rswz)];
      }
      if (tt + 2 < nt) {
        int bi = cur + 2; if (bi >= 3) bi -= 3;
        stageB(BT, ld, bi, tt + 2);
      }
      __builtin_amdgcn_s_setprio(1);
#pragma unroll
      for (int kk = 0; kk < 2; ++kk)
#pragma unroll
        for (int m = 0; m < 2; ++m)
#pragma unroll
          for (int n = 0; n < 4; ++n)
            acc[m][n] = __builtin_amdgcn_mfma_f32_16x16x32_bf16(av[kk][m], bv[kk][n],
                                                                acc[m][n], 0, 0, 0);
      __builtin_amdgcn_s_setprio(0);
      if (tt < nt - 2) {
        asm volatile("s_waitcnt vmcnt(4)" ::: "memory");
        __builtin_amdgcn_s_barrier();
      } else if (tt == nt - 2) {
        asm volatile("s_waitcnt vmcnt(0)" ::: "memory");
        __builtin_amdgcn_s_barrier();
      }
      ++cur; if (cur == 3) cur = 0;
    }
  };

  f32x4 zreg[2][4], hreg[2][4];

  // ---- pass z ----
  run(wzr, 256, 4);
#pragma unroll
  for (int m = 0; m < 2; ++m)
#pragma unroll
    for (int n = 0; n < 4; ++n) {
      const int col = wc * 64 + n * 16 + lr;
      const float zb = ugb[col];
#pragma unroll
      for (int r = 0; r < 4; ++r) zreg[m][n][r] = sigm(acc[m][n][r] + zb);
    }
  __syncthreads();

  // ---- pass r ----
  stageB(wzr + 128 * 256, 256, 0, 0);
  stageB(wzr + 128 * 256, 256, 1, 1);
  asm volatile("s_waitcnt vmcnt(4)" ::: "memory");
  __builtin_amdgcn_s_barrier();
  run(wzr + 128 * 256, 256, 4);
  __syncthreads();  // all waves done reading A tiles 0,1
  stageB(htW, 256, 0, 0);
  stageB(htW, 256, 1, 1);
#pragma unroll
  for (int m = 0; m < 2; ++m)
#pragma unroll
    for (int n = 0; n < 4; ++n) {
      const int col = wc * 64 + n * 16 + lr;
      const int ti = col >> 6, cole = col & 63;
      const float rb = rgb[col];
#pragma unroll
      for (int r = 0; r < 4; ++r) {
        const int lrow = wr * 32 + m * 16 + lh * 4 + r;
        const float hv = hF[(size_t)(bm * 64 + lrow) * DQ + col];
        hreg[m][n][r] = hv;
        const float rr = sigm(acc[m][n][r] + rb);
        Asm[ti * 4096 + lrow * 64 + (((cole >> 3) ^ (lrow & 7)) << 3) + (cole & 7)] =
            __float2bfloat16(rr * hv);
      }
    }
  asm volatile("s_waitcnt vmcnt(4) lgkmcnt(0)" ::: "memory");
  __builtin_amdgcn_s_barrier();

  // ---- pass ht ----
  run(htW, 256, 4);
  __syncthreads();

  if constexpr (DO_IN) {
    stageB(inWn, 128, 0, 0);
    stageB(inWn, 128, 1, 1);
#pragma unroll
    for (int m = 0; m < 2; ++m)
#pragma unroll
      for (int n = 0; n < 4; ++n) {
        const int col = wc * 64 + n * 16 + lr;
        const int ti = col >> 6, cole = col & 63;
        const float hb = htb[col];
#pragma unroll
        for (int r = 0; r < 4; ++r) {
          const int lrow = wr * 32 + m * 16 + lh * 4 + r;
          const float tv = tanhf(acc[m][n][r] + hb);
          const float zv = zreg[m][n][r];
          const float hn = zv * hreg[m][n][r] + (1.f - zv) * tv;
          Asm[ti * 4096 + lrow * 64 + (((cole >> 3) ^ (lrow & 7)) << 3) + (cole & 7)] =
              __float2bfloat16(hn);
        }
      }
    asm volatile("s_waitcnt vmcnt(4) lgkmcnt(0)" ::: "memory");
    __builtin_amdgcn_s_barrier();
    // ---- pass in-proj (next block) ----
    run(inWn, 128, 2);
#pragma unroll
    for (int m = 0; m < 2; ++m) {
      const int gRow = bm * 64 + wr * 32 + m * 16 + lh * 4;
#pragma unroll
      for (int n = 0; n < 4; ++n) {
        const int col = wc * 64 + n * 16 + lr;
        const float ib = inbn[col];
        float hv[4];
#pragma unroll
        for (int r = 0; r < 4; ++r) {
          const float hn = acc[m][n][r] + ib;
          hv[r] = hn;
          hF[(size_t)(gRow + r) * DQ + col] = hn;
          hbf[(size_t)(gRow + r) * DQ + col] = __float2bfloat16(hn);
        }
        unsigned int pk = __builtin_amdgcn_cvt_pk_fp8_f32(hv[0], hv[1], 0u, false);
        pk = __builtin_amdgcn_cvt_pk_fp8_f32(hv[2], hv[3], pk, true);
        const int bb_ = gRow >> 11;
        const int nl = gRow & 2047;
        const int pd = (nl & ~127) | pi128(nl & 127);
        *(unsigned int*)(hT8 + (size_t)bb_ * (DQ * NQ) + (size_t)col * NQ + pd) = pk;
      }
    }
  } else {
#pragma unroll
    for (int m = 0; m < 2; ++m) {
      const int gRow = bm * 64 + wr * 32 + m * 16 + lh * 4;
#pragma unroll
      for (int n = 0; n < 4; ++n) {
        const int col = wc * 64 + n * 16 + lr;
        const float hb = htb[col];
        float hv[4];
#pragma unroll
        for (int r = 0; r < 4; ++r) {
          const float tv = tanhf(acc[m][n][r] + hb);
          const float zv = zreg[m][n][r];
          const float hn = zv * hreg[m][n][r] + (1.f - zv) * tv;
          hv[r] = hn;
          hF[(size_t)(gRow + r) * DQ + col] = hn;
          hbf[(size_t)(gRow + r) * DQ + col] = __float2bfloat16(hn);
        }
        unsigned int pk = __builtin_amdgcn_cvt_pk_fp8_f32(hv[0], hv[1], 0u, false);
        pk = __builtin_amdgcn_cvt_pk_fp8_f32(hv[2], hv[3], pk, true);
        const int bb_ = gRow >> 11;
        const int nl = gRow & 2047;
        const int pd = (nl & ~127) | pi128(nl & 127);
        *(unsigned int*)(hT8 + (size_t)bb_ * (DQ * NQ) + (size_t)col * NQ + pd) = pk;
      }
    }
  }
}

// ---------------------------------------------------------------------------
// in0: build x (embeddings) into LDS + in-proj block 0. 256 blocks x 64 rows.
// ---------------------------------------------------------------------------
__global__ __launch_bounds__(256, 2) void in0_k(
    const int* __restrict__ node, const int* __restrict__ text,
    const int* __restrict__ line,
    const float* __restrict__ te, const float* __restrict__ te1,
    const __hip_bfloat16* __restrict__ inW, const float* __restrict__ inb,
    float* __restrict__ hF, __hip_bfloat16* __restrict__ hbf,
    unsigned char* __restrict__ hT8) {
  __shared__ __align__(16) __hip_bfloat16 Asm[2 * 4096];
  __shared__ __align__(16) __hip_bfloat16 Bsm[2 * 8192];
  const int t = threadIdx.x, lane = t & 63, w = t >> 6;
  const int wr = (w >> 1) & 1, wc = w & 1;
  const int bm = blockIdx.x;
  const int lr = lane & 15, lh = lane >> 4;
  const int rswz = (lr & 7) << 3;
  const int swzCol = ((lane & 7) ^ (lane >> 3)) << 3;
  const int srow = lane >> 3;

#pragma unroll
  for (int bi = 0; bi < 2; ++bi)
#pragma unroll
    for (int q = 0; q < 4; ++q)
      g2l16(inW + (size_t)(w * 32 + q * 8 + srow) * 128 + bi * 64 + swzCol,
            (char*)Bsm + bi * 16384 + w * 4096 + q * 1024);

  {
    const int lrow = t >> 2;             // 0..63
    const int gRow = bm * 64 + lrow;
    const int b = gRow >> 11, p = gRow & 2047;
    const int c0 = (t & 3) * 32;
    float vals[32];
    if (p < NLQ) {
      const int id = node[b * NLQ + p];
      const float tx = (float)text[b * NLQ + p];
#pragma unroll
      for (int j = 0; j < 32; ++j) {
        const int col = c0 + j;
        vals[j] = (col < 127) ? te[(size_t)id * 127 + col] : tx;
      }
    } else {
      const int id = line[b * NLQ + (p - NLQ)];
#pragma unroll
      for (int j = 0; j < 32; ++j) vals[j] = te1[(size_t)id * 128 + c0 + j];
    }
#pragma unroll
    for (int k = 0; k < 4; ++k) {
      const int col = c0 + k * 8;
      const int ti = col >> 6, cole = col & 63;
      uint4 u;
      u.x = pk2(vals[k * 8 + 0], vals[k * 8 + 1]);
      u.y = pk2(vals[k * 8 + 2], vals[k * 8 + 3]);
      u.z = pk2(vals[k * 8 + 4], vals[k * 8 + 5]);
      u.w = pk2(vals[k * 8 + 6], vals[k * 8 + 7]);
      *(uint4*)((char*)Asm + ti * 8192 + lrow * 128 +
                (((cole >> 3) ^ (lrow & 7)) << 4)) = u;
    }
  }
  __syncthreads();  // drains vmcnt + lgkm: B and A both ready

  f32x4 acc[2][4] = {};
  for (int tt = 0; tt < 2; ++tt) {
    bf16x8 av[2][2], bv[2][4];
#pragma unroll
    for (int kk = 0; kk < 2; ++kk) {
#pragma unroll
      for (int m = 0; m < 2; ++m)
        av[kk][m] = *(const bf16x8*)&Asm[tt * 4096 + (wr * 32 + m * 16 + lr) * 64 +
                                        ((kk * 32 + lh * 8) ^ rswz)];
#pragma unroll
      for (int n = 0; n < 4; ++n)
        bv[kk][n] = *(const bf16x8*)&Bsm[tt * 8192 + (wc * 64 + n * 16 + lr) * 64 +
                                         ((kk * 32 + lh * 8) ^ rswz)];
    }
#pragma unroll
    for (int kk = 0; kk < 2; ++kk)
#pragma unroll
      for (int m = 0; m < 2; ++m)
#pragma unroll
        for (int n = 0; n < 4; ++n)
          acc[m][n] = __builtin_amdgcn_mfma_f32_16x16x32_bf16(av[kk][m], bv[kk][n],
                                                              acc[m][n], 0, 0, 0);
  }
#pragma unroll
  for (int m = 0; m < 2; ++m) {
    const int gRow = bm * 64 + wr * 32 + m * 16 + lh * 4;
#pragma unroll
    for (int n = 0; n < 4; ++n) {
      const int col = wc * 64 + n * 16 + lr;
      const float ib = inb[col];
      float hv[4];
#pragma unroll
      for (int r = 0; r < 4; ++r) {
        const float hn = acc[m][n][r] + ib;
        hv[r] = hn;
        hF[(size_t)(gRow + r) * DQ + col] = hn;
        hbf[(size_t)(gRow + r) * DQ + col] = __float2bfloat16(hn);
      }
      unsigned int pk = __builtin_amdgcn_cvt_pk_fp8_f32(hv[0], hv[1], 0u, false);
      pk = __builtin_amdgcn_cvt_pk_fp8_f32(hv[2], hv[3], pk, true);
      const int bb_ = gRow >> 11;
      const int nl = gRow & 2047;
      const int pd = (nl & ~127) | pi128(nl & 127);
      *(unsigned int*)(hT8 + (size_t)bb_ * (DQ * NQ) + (size_t)col * NQ + pd) = pk;
    }
  }
}

// ---------------------------------------------------------------------------
// adj fp32 -> fp8 e4m3 x 2^13, pi-permuted per 128-chunk.
__global__ void cvt_adj(const float4* __restrict__ in, unsigned char* __restrict__ out,
                        int n4) {
  int stride = gridDim.x * blockDim.x;
  for (int i = blockIdx.x * blockDim.x + threadIdx.x; i < n4; i += stride) {
    float4 v = in[i];
    unsigned int pk = __builtin_amdgcn_cvt_pk_fp8_f32(v.x * 8192.f, v.y * 8192.f, 0u, false);
    pk = __builtin_amdgcn_cvt_pk_fp8_f32(v.z * 8192.f, v.w * 8192.f, pk, true);
    const int g = i << 2;
    const int dst = (g & ~127) | pi128(g & 127);
    *(unsigned int*)(out + dst) = pk;
  }
}

// Pack weights to bf16, transposed to N x K row-major.
__global__ void pack_weights(const float* __restrict__ ugW, const float* __restrict__ rgW,
                             const float* __restrict__ htW, const float* __restrict__ inW,
                             __hip_bfloat16* __restrict__ wzrT, __hip_bfloat16* __restrict__ htT,
                             __hip_bfloat16* __restrict__ inT) {
  int idx = blockIdx.x * 256 + threadIdx.x;
  if (idx < 5 * 256 * 256) {  // wzrT[i][n][k], n<128 -> ug, else rg
    int i = idx >> 16, r = idx & 65535, nn = r >> 8, k = r & 255;
    float v = (nn < 128) ? ugW[(i * 256 + k) * 128 + nn] : rgW[(i * 256 + k) * 128 + nn - 128];
    wzrT[idx] = __float2bfloat16(v);
    return;
  }
  int j = idx - 5 * 256 * 256;
  if (j < 5 * 128 * 256) {  // htT[i][n][k]
    int i = j >> 15, r = j & 32767, nn = r >> 8, k = r & 255;
    htT[j] = __float2bfloat16(htW[(i * 256 + k) * 128 + nn]);
    return;
  }
  int j2 = j - 5 * 256 * 128;
  if (j2 < 5 * 128 * 128) {  // inT[i][n][k]
    int i = j2 >> 14, r = j2 & 16383, nn = r >> 7, k = r & 127;
    inT[j2] = __float2bfloat16(inW[(i * 128 + k) * 128 + nn]);
  }
}

__device__ __forceinline__ float waveMax(float v) {
#pragma unroll
  for (int m = 32; m; m >>= 1) v = fmaxf(v, __shfl_xor(v, m, 64));
  return v;
}
__device__ __forceinline__ float waveSum(float v) {
#pragma unroll
  for (int m = 32; m; m >>= 1) v += __shfl_xor(v, m, 64);
  return v;
}

// logits + mask + softmax + loss; also copies x rows to outX. 1 row/thread.
__global__ __launch_bounds__(1024) void final_k(const float* __restrict__ h,
                                                const float* __restrict__ w2,
                                                const float* __restrict__ b2,
                                                const int* __restrict__ node,
                                                const float* __restrict__ res,
                                                float* __restrict__ outLoss,
                                                float* __restrict__ outSm,
                                                float* __restrict__ outX) {
  int b = blockIdx.x, t = threadIdx.x;
  __shared__ float lw[128];
  __shared__ float red[16];
  __shared__ float bc;
  if (t < 128) lw[t] = w2[t];
  __syncthreads();
  const float* hr = h + ((size_t)b * NQ + t) * DQ;
  float* xr = outX + ((size_t)b * NLQ + t) * DQ;
  float s = 0.f;
#pragma unroll
  for (int d = 0; d < 128; d += 4) {
    float4 hv = *(const float4*)(hr + d);
    *(float4*)(xr + d) = hv;
    s += hv.x * lw[d] + hv.y * lw[d + 1] + hv.z * lw[d + 2] + hv.w * lw[d + 3];
  }
  float lg = (node[b * NLQ + t] == 2) ? (s + b2[0]) : -1e9f;
  int lane = t & 63, w = t >> 6;
  float mx = waveMax(lg);
  if (lane == 0) red[w] = mx;
  __syncthreads();
  if (t == 0) {
    float m = red[0];
#pragma unroll
    for (int i = 1; i < 16; ++i) m = fmaxf(m, red[i]);
    bc = m;
  }
  __syncthreads();
  float M = bc;
  float e = expf(lg - M);
  float sum = waveSum(e);
  __syncthreads();
  if (lane == 0) red[w] = sum;
  __syncthreads();
  if (t == 0) {
    float tot = 0.f;
#pragma unroll
    for (int i = 0; i < 16; ++i) tot += red[i];
    bc = tot;
  }
  __syncthreads();
  float sm = e / bc;
  outSm[b * NLQ + t] = sm;
  float c = fminf(fmaxf(sm, 1e-10f), 1.f);
  float loss = waveSum(-logf(c) * res[b * NLQ + t]);
  __syncthreads();
  if (lane == 0) red[w] = loss;
  __syncthreads();
  if (t == 0) {
    float tot = 0.f;
#pragma unroll
    for (int i = 0; i < 16; ++i) tot += red[i];
    outLoss[b] = tot;
  }
}

__global__ void ws_fail(float* out) {
  if (threadIdx.x == 0) out[0] = -7.0e7f;  // sentinel: workspace too small
}

// ---------------------------------------------------------------------------
extern "C" void kernel_launch(void* const* d_in, const int* in_sizes, int n_in,
                              void* d_out, int out_size, void* d_ws, size_t ws_size,
                              hipStream_t stream) {
  const int* input_node = (const int*)d_in[0];
  const float* inputad  = (const float*)d_in[2];
  const float* res      = (const float*)d_in[3];
  const int* inputtext  = (const int*)d_in[4];
  const int* linenode   = (const int*)d_in[5];
  const float* tok_emb  = (const float*)d_in[8];
  const float* tok_emb1 = (const float*)d_in[9];
  const float* in_W  = (const float*)d_in[10];
  const float* in_b  = (const float*)d_in[11];
  const float* ug_W  = (const float*)d_in[12];
  const float* ug_b  = (const float*)d_in[13];
  const float* rg_W  = (const float*)d_in[14];
  const float* rg_b  = (const float*)d_in[15];
  const float* ht_W  = (const float*)d_in[16];
  const float* ht_b  = (const float*)d_in[17];
  const float* res2_W = (const float*)d_in[18];
  const float* res2_b = (const float*)d_in[19];

  char* ws = (char*)d_ws;
  const size_t OFF_ADJ = 0;
  const size_t OFF_H   = OFF_ADJ + (size_t)BQ * NQ * NQ;           // adj fp8, 34 MB
  const size_t OFF_HBF = OFF_H   + (size_t)BQ * NQ * DQ * 4;       // h fp32
  const size_t OFF_HT8 = OFF_HBF + (size_t)BQ * NQ * DQ * 2;       // h bf16 row-major
  const size_t OFF_MS  = OFF_HT8 + (size_t)BQ * NQ * DQ;           // hT fp8 [b][d][n]
  const size_t OFF_WZR = OFF_MS  + (size_t)2 * BQ * NQ * DQ * 2;   // msgs partials x2
  const size_t OFF_HTW = OFF_WZR + (size_t)5 * 256 * 256 * 2;
  const size_t OFF_INW = OFF_HTW + (size_t)5 * 128 * 256 * 2;
  const size_t NEED    = OFF_INW + (size_t)5 * 128 * 128 * 2;      // ~57 MB
  if (ws_size < NEED) {
    ws_fail<<<1, 64, 0, stream>>>((float*)d_out);
    return;
  }

  unsigned char* adj8   = (unsigned char*)(ws + OFF_ADJ);
  float* hF             = (float*)(ws + OFF_H);
  __hip_bfloat16* hbf   = (__hip_bfloat16*)(ws + OFF_HBF);
  unsigned char* hT8    = (unsigned char*)(ws + OFF_HT8);
  __hip_bfloat16* msbf  = (__hip_bfloat16*)(ws + OFF_MS);
  __hip_bfloat16* wzrT  = (__hip_bfloat16*)(ws + OFF_WZR);
  __hip_bfloat16* htTw  = (__hip_bfloat16*)(ws + OFF_HTW);
  __hip_bfloat16* inTw  = (__hip_bfloat16*)(ws + OFF_INW);

  float* outLoss = (float*)d_out;
  float* outSm = outLoss + BQ;
  float* outX = outSm + BQ * NLQ;

  pack_weights<<<2240, 256, 0, stream>>>(ug_W, rg_W, ht_W, in_W, wzrT, htTw, inTw);
  in0_k<<<256, 256, 0, stream>>>(input_node, inputtext, linenode, tok_emb, tok_emb1,
                                 inTw, in_b, hF, hbf, hT8);
  cvt_adj<<<4096, 256, 0, stream>>>((const float4*)inputad, adj8,
                                    (int)((size_t)BQ * NQ * NQ / 4));

  for (int i = 0; i < 5; ++i) {
    for (int s = 0; s < 3; ++s) {
      gemm_msgs<<<dim3(32, 1, 16), 256, 0, stream>>>(adj8, hT8, msbf);
      const bool doin = (s == 2 && i < 4);
      if (doin)
        gru_k<true><<<256, 256, 0, stream>>>(
            hbf, msbf, wzrT + i * 65536, htTw + i * 32768, inTw + (i + 1) * 16384,
            ug_b + i * 128, rg_b + i * 128, ht_b + i * 128, in_b + (i + 1) * 128,
            hF, hbf, hT8);
      else
        gru_k<false><<<256, 256, 0, stream>>>(
            hbf, msbf, wzrT + i * 65536, htTw + i * 32768, nullptr,
            ug_b + i * 128, rg_b + i * 128, ht_b + i * 128, nullptr,
            hF, hbf, hT8);
    }
  }

  final_k<<<8, 1024, 0, stream>>>(hF, res2_W, res2_b, input_node, res,
                                  outLoss, outSm, outX);
}